// Round 5
// baseline (120.751 us; speedup 1.0000x reference)
//
#include <hip/hip_runtime.h>

// ---------------------------------------------------------------------------
// PAM module: [prep weights] -> fused conv3x3s2+qkv (bf16 MFMA implicit GEMM)
// -> flash attention (16x16 MFMA, in-block KV-split x4, LDS P-transpose PV)
// -> bilinear upsample + residual.
// Shapes: x[8][64][128][128] f32, pooled h=w=64 -> N=4096, d_qk=32, d_v=64.
// ---------------------------------------------------------------------------

typedef __attribute__((ext_vector_type(8))) short bf16x8;   // 8 bf16 (4 VGPRs)
typedef __attribute__((ext_vector_type(4))) float f32x4;

#define DEV static __device__ __forceinline__

DEV unsigned f2bf(float f) {                  // RNE f32 -> bf16 bits
  union { float f; unsigned u; } a; a.f = f;
  return (a.u + 0x7FFFu + ((a.u >> 16) & 1u)) >> 16;
}
DEV unsigned cvtpk(float lo, float hi) {      // v_cvt_pk_bf16_f32 (RNE, 1 instr)
  unsigned r;
  asm("v_cvt_pk_bf16_f32 %0, %1, %2" : "=v"(r) : "v"(lo), "v"(hi));
  return r;
}
DEV bf16x8 mk_bf16x8(unsigned w0, unsigned w1, unsigned w2, unsigned w3) {
  union { unsigned u[4]; bf16x8 v; } x;
  x.u[0] = w0; x.u[1] = w1; x.u[2] = w2; x.u[3] = w3;
  return x.v;
}

// ---------------------------------------------------------------------------
// Kernel 0: weight prep.  Ag[oc][k=tap*64+ic] bf16 (conv A-operand, K=576);
// A2g[row][ic] bf16 (rows 0-31 q_w, 32-63 k_w, 64-127 v_w); bias2[128] f32.
// ---------------------------------------------------------------------------
__global__ __launch_bounds__(256) void prep_kernel(
    const float* __restrict__ pw, const float* __restrict__ qw,
    const float* __restrict__ kw, const float* __restrict__ vw,
    const float* __restrict__ qb, const float* __restrict__ kb,
    const float* __restrict__ vb,
    unsigned short* __restrict__ Ag, unsigned short* __restrict__ A2g,
    float* __restrict__ bias2) {
  const int i = blockIdx.x * 256 + threadIdx.x;
  if (i < 36864) {
    const int oc = i / 576, k = i - oc * 576;
    const int tap = k >> 6, ic = k & 63;
    Ag[i] = (unsigned short)f2bf(pw[(oc * 64 + ic) * 9 + tap]);
  }
  const int j = i - 36864;
  if (j >= 0 && j < 8192) {
    const int r = j >> 6, c = j & 63;
    const float* src = r < 32 ? qw + r * 64 : (r < 64 ? kw + (r - 32) * 64
                                                      : vw + (r - 64) * 64);
    A2g[j] = (unsigned short)f2bf(src[c]);
  }
  if (j >= 8192 && j < 8320) {
    const int r = j - 8192;
    bias2[r] = r < 32 ? qb[r] : (r < 64 ? kb[r - 32] : vb[r - 64]);
  }
}

// ---------------------------------------------------------------------------
// Kernel 1: fused conv3x3s2 + qkv, bf16 MFMA 16x16x32 (round-2 verified).
// ---------------------------------------------------------------------------
__global__ __launch_bounds__(256) void convqkv_kernel(
    const float* __restrict__ x, const unsigned short* __restrict__ Ag,
    const float* __restrict__ pool_b, const unsigned short* __restrict__ A2g,
    const float* __restrict__ bias2,
    unsigned short* __restrict__ qT, unsigned short* __restrict__ kT,
    unsigned short* __restrict__ vM) {
  const int b = blockIdx.x >> 6, oy = blockIdx.x & 63;
  const int t = threadIdx.x, w = t >> 6, lane = t & 63;
  const int lr = lane & 15, lg = lane >> 4;
  __shared__ unsigned short sIn[390 * 64];   // 48.75 KB, swizzled bytes
  __shared__ unsigned short sXP[64 * 64];    // 8 KB, swizzled bytes
  char* sInB = (char*)sIn;
  char* sXPB = (char*)sXP;

  bf16x8 af[18];
  {
    const unsigned short* ap = Ag + (w * 16 + lr) * 576 + (lg << 3);
    #pragma unroll
    for (int kc = 0; kc < 18; ++kc)
      af[kc] = *(const bf16x8*)(ap + kc * 32);
  }

  #pragma unroll
  for (int rr = 0; rr < 2; ++rr) {
    const int pos = t + rr * 256;
    if (pos < 390) {
      const int ky = pos / 130, xi = pos - ky * 130;
      const int iy = 2 * oy + ky - 1, ix = xi - 1;
      const bool ok = (iy >= 0) & (iy < 128) & (ix >= 0) & (ix < 128);
      const float* xs = x + ((size_t)(b * 64) * 128 + (ok ? iy : 0)) * 128 +
                        (ok ? ix : 0);
      const int sw = pos & 7;
      #pragma unroll
      for (int o = 0; o < 8; ++o) {
        float f[8];
        #pragma unroll
        for (int jj = 0; jj < 8; ++jj)
          f[jj] = ok ? xs[(size_t)(o * 8 + jj) * 16384] : 0.f;
        bf16x8 v = mk_bf16x8(cvtpk(f[0], f[1]), cvtpk(f[2], f[3]),
                             cvtpk(f[4], f[5]), cvtpk(f[6], f[7]));
        *(bf16x8*)(sInB + pos * 128 + ((o ^ sw) << 4)) = v;
      }
    }
  }
  __syncthreads();

  f32x4 acc[4];
  #pragma unroll
  for (int nt = 0; nt < 4; ++nt) acc[nt] = (f32x4){0.f, 0.f, 0.f, 0.f};
  #pragma unroll
  for (int kc = 0; kc < 18; ++kc) {
    const int tap = kc >> 1, ky = tap / 3, kx = tap - ky * 3;
    const int o = ((kc & 1) << 2) + lg;
    #pragma unroll
    for (int nt = 0; nt < 4; ++nt) {
      const int xi = 2 * (nt * 16 + lr) + kx;
      const int pos = ky * 130 + xi;
      bf16x8 bfr = *(const bf16x8*)(sInB + pos * 128 + ((o ^ (pos & 7)) << 4));
      acc[nt] = __builtin_amdgcn_mfma_f32_16x16x32_bf16(af[kc], bfr, acc[nt],
                                                        0, 0, 0);
    }
  }

  const int ocBase = w * 16 + (lg << 2);
  float pb[4];
  #pragma unroll
  for (int r = 0; r < 4; ++r) pb[r] = pool_b[ocBase + r];
  const int ocOct = ocBase >> 3;
  const int withinB = (ocBase & 7) * 2;
  #pragma unroll
  for (int nt = 0; nt < 4; ++nt) {
    const int pos = nt * 16 + lr;
    const unsigned p01 = cvtpk(acc[nt][0] + pb[0], acc[nt][1] + pb[1]);
    const unsigned p23 = cvtpk(acc[nt][2] + pb[2], acc[nt][3] + pb[3]);
    char* base = sXPB + pos * 128 + ((ocOct ^ (pos & 7)) << 4) + withinB;
    *(unsigned*)(base) = p01;
    *(unsigned*)(base + 4) = p23;
  }
  __syncthreads();

  bf16x8 a2[2][2];
  #pragma unroll
  for (int mt = 0; mt < 2; ++mt)
    #pragma unroll
    for (int kc2 = 0; kc2 < 2; ++kc2)
      a2[mt][kc2] = *(const bf16x8*)(A2g + ((2 * w + mt) * 16 + lr) * 64 +
                                     kc2 * 32 + (lg << 3));
  f32x4 acc2[2][4];
  #pragma unroll
  for (int mt = 0; mt < 2; ++mt)
    #pragma unroll
    for (int nt = 0; nt < 4; ++nt) acc2[mt][nt] = (f32x4){0.f, 0.f, 0.f, 0.f};
  #pragma unroll
  for (int kc2 = 0; kc2 < 2; ++kc2) {
    const int o2 = (kc2 << 2) + lg;
    #pragma unroll
    for (int nt = 0; nt < 4; ++nt) {
      const int pos = nt * 16 + lr;
      bf16x8 bfr = *(const bf16x8*)(sXPB + pos * 128 + ((o2 ^ (pos & 7)) << 4));
      acc2[0][nt] = __builtin_amdgcn_mfma_f32_16x16x32_bf16(a2[0][kc2], bfr,
                                                            acc2[0][nt], 0, 0, 0);
      acc2[1][nt] = __builtin_amdgcn_mfma_f32_16x16x32_bf16(a2[1][kc2], bfr,
                                                            acc2[1][nt], 0, 0, 0);
    }
  }

  const int n0g = oy << 6;
  #pragma unroll
  for (int mt = 0; mt < 2; ++mt) {
    const int rowB = (2 * w + mt) * 16 + (lg << 2);
    float b2[4];
    #pragma unroll
    for (int r = 0; r < 4; ++r) b2[r] = bias2[rowB + r];
    if (rowB < 32) {
      #pragma unroll
      for (int nt = 0; nt < 4; ++nt) {
        const int n = n0g + nt * 16 + lr;
        unsigned* dst = (unsigned*)(qT + (((size_t)(b << 12) + n) << 5) + rowB);
        dst[0] = cvtpk(acc2[mt][nt][0] + b2[0], acc2[mt][nt][1] + b2[1]);
        dst[1] = cvtpk(acc2[mt][nt][2] + b2[2], acc2[mt][nt][3] + b2[3]);
      }
    } else if (rowB < 64) {
      #pragma unroll
      for (int nt = 0; nt < 4; ++nt) {
        const int n = n0g + nt * 16 + lr;
        unsigned* dst = (unsigned*)(kT + (((size_t)(b << 12) + n) << 5) + rowB - 32);
        dst[0] = cvtpk(acc2[mt][nt][0] + b2[0], acc2[mt][nt][1] + b2[1]);
        dst[1] = cvtpk(acc2[mt][nt][2] + b2[2], acc2[mt][nt][3] + b2[3]);
      }
    } else {
      const int cv = rowB - 64;
      #pragma unroll
      for (int nt = 0; nt < 4; ++nt) {
        const int n = n0g + nt * 16 + lr;
        #pragma unroll
        for (int r = 0; r < 4; ++r)
          vM[(((size_t)(b << 6) + cv + r) << 12) + n] =
              (unsigned short)f2bf(acc2[mt][nt][r] + b2[r]);
      }
    }
  }
}

// ---------------------------------------------------------------------------
// Kernel 2: flash attention (round-2 verified base + 3 optimizations).
// Block = (b, 32-query tile); wave w handles keys [w*1024, +1024).
// Opt 1: PV P-redistribution via per-wave LDS transpose (12 DS ops/chunk,
//        was 32 ds_bpermute + 16 cndmask).  P buffer [query 32][key 64] bf16,
//        row stride 144B (pad breaks 128B bank wrap), 8B-slot XOR swizzle.
//        Overlays the (loop-dead) merge region; same-wave produce/consume.
// Opt 2: per-chunk l-sum kept as per-lane partials; one shfl-reduce at end.
// Opt 3: s_setprio(1) around MFMA clusters (T5).
// ---------------------------------------------------------------------------
__global__ __launch_bounds__(256) void attn_kernel(
    const unsigned short* __restrict__ qT, const unsigned short* __restrict__ kT,
    const unsigned short* __restrict__ vM, const float* __restrict__ gamma_p,
    float* __restrict__ attn_out) {
  const int t = threadIdx.x;
  const int b = blockIdx.x & 7;
  const int u = blockIdx.x >> 3;            // 0..127 query tile
  const int n0 = u << 5;
  const int w = t >> 6;                     // KV split
  const int lane = t & 63, lr = lane & 15, lg = lane >> 4;
  __shared__ float sAcc[4 * 64 * 32];       // 32 KB: Pb (loop) / merge (post)
  __shared__ float sM[4][2][16], sL[4][2][16];
  char* sAB = (char*)sAcc;
  char* Pw = sAB + (w << 13);               // this wave's P buffer (4608 B used)
  const int swz2 = (lr & 7) << 1;           // even 8B-slot XOR mask (row-keyed)

  const unsigned short* qp = qT + (((size_t)(b << 12) + n0 + lr) << 5) + (lg << 3);
  const bf16x8 bq0 = *(const bf16x8*)(qp);
  const bf16x8 bq1 = *(const bf16x8*)(qp + (16 << 5));

  const int kvbase = w << 10;
  const unsigned short* kbase =
      kT + (((size_t)(b << 12) + kvbase + lr) << 5) + (lg << 3);
  const unsigned short* vbase =
      vM + (((size_t)(b << 6) + lr) << 12) + kvbase + (lg << 3);

  f32x4 acc[2][4];
  #pragma unroll
  for (int i = 0; i < 2; ++i)
    #pragma unroll
    for (int j = 0; j < 4; ++j) acc[i][j] = (f32x4){0.f, 0.f, 0.f, 0.f};
  float m_run[2] = {-1e30f, -1e30f};
  float l_run[2] = {0.f, 0.f};

  bf16x8 ka[4];
  #pragma unroll
  for (int j = 0; j < 4; ++j)
    ka[j] = *(const bf16x8*)(kbase + ((size_t)(16 * j) << 5));

  for (int km = 0; km < 1024; km += 64) {
    bf16x8 va[2][4];
    #pragma unroll
    for (int h = 0; h < 2; ++h)
      #pragma unroll
      for (int ct = 0; ct < 4; ++ct)
        va[h][ct] = *(const bf16x8*)(
            vbase + ((size_t)(ct << 4) << 12) + km + (h << 5));
    const int kmn = (km + 64) & 1023;
    bf16x8 kn[4];
    #pragma unroll
    for (int j = 0; j < 4; ++j)
      kn[j] = *(const bf16x8*)(kbase + ((size_t)(kmn + 16 * j) << 5));

    f32x4 st[2][4];
    const f32x4 z4 = {0.f, 0.f, 0.f, 0.f};
    __builtin_amdgcn_s_setprio(1);
    #pragma unroll
    for (int j = 0; j < 4; ++j) {
      st[0][j] = __builtin_amdgcn_mfma_f32_16x16x32_bf16(ka[j], bq0, z4, 0, 0, 0);
      st[1][j] = __builtin_amdgcn_mfma_f32_16x16x32_bf16(ka[j], bq1, z4, 0, 0, 0);
    }
    __builtin_amdgcn_s_setprio(0);

    unsigned pw_[2][4][2];
    #pragma unroll
    for (int nt = 0; nt < 2; ++nt) {
      // balanced max tree over this lane's 16 scores
      float m01 = fmaxf(fmaxf(st[nt][0][0], st[nt][0][1]),
                        fmaxf(st[nt][0][2], st[nt][0][3]));
      float m23 = fmaxf(fmaxf(st[nt][1][0], st[nt][1][1]),
                        fmaxf(st[nt][1][2], st[nt][1][3]));
      float m45 = fmaxf(fmaxf(st[nt][2][0], st[nt][2][1]),
                        fmaxf(st[nt][2][2], st[nt][2][3]));
      float m67 = fmaxf(fmaxf(st[nt][3][0], st[nt][3][1]),
                        fmaxf(st[nt][3][2], st[nt][3][3]));
      float cm = fmaxf(fmaxf(m01, m23), fmaxf(m45, m67));
      cm = fmaxf(cm, __shfl_xor(cm, 16, 64));
      cm = fmaxf(cm, __shfl_xor(cm, 32, 64));
      if (!__all(cm <= m_run[nt] + 8.0f)) {   // defer-max (T13)
        const float mnew = fmaxf(m_run[nt], cm);
        const float sc = __expf(m_run[nt] - mnew);
        m_run[nt] = mnew;
        l_run[nt] *= sc;
        #pragma unroll
        for (int ct = 0; ct < 4; ++ct) acc[nt][ct] *= sc;
      }
      const float mm = m_run[nt];
      float ps = 0.f;
      #pragma unroll
      for (int j = 0; j < 4; ++j) {
        const float p0 = __expf(st[nt][j][0] - mm);
        const float p1 = __expf(st[nt][j][1] - mm);
        const float p2 = __expf(st[nt][j][2] - mm);
        const float p3 = __expf(st[nt][j][3] - mm);
        ps += (p0 + p1) + (p2 + p3);
        pw_[nt][j][0] = cvtpk(p0, p1);
        pw_[nt][j][1] = cvtpk(p2, p3);
      }
      l_run[nt] += ps;                        // per-lane partial (reduced at end)
    }

    // ---- P transpose via LDS: write keys 16j+4lg..+3 at row (query) nt*16+lr
    #pragma unroll
    for (int nt = 0; nt < 2; ++nt)
      #pragma unroll
      for (int j = 0; j < 4; ++j) {
        const int slot = ((j << 2) + lg) ^ swz2;
        *(uint2*)(Pw + (nt * 16 + lr) * 144 + (slot << 3)) =
            (uint2){pw_[nt][j][0], pw_[nt][j][1]};
      }

    // ---- PV: B-frag = P[q=nt*16+lr][keys 32h+8lg..+7] as one b128 read
    #pragma unroll
    for (int h = 0; h < 2; ++h) {
      #pragma unroll
      for (int nt = 0; nt < 2; ++nt) {
        const int srd = ((h << 3) + (lg << 1)) ^ swz2;
        const bf16x8 pbf =
            *(const bf16x8*)(Pw + (nt * 16 + lr) * 144 + (srd << 3));
        __builtin_amdgcn_s_setprio(1);
        #pragma unroll
        for (int ct = 0; ct < 4; ++ct)
          acc[nt][ct] = __builtin_amdgcn_mfma_f32_16x16x32_bf16(va[h][ct], pbf,
                                                                acc[nt][ct], 0, 0, 0);
        __builtin_amdgcn_s_setprio(0);
      }
    }
    #pragma unroll
    for (int j = 0; j < 4; ++j) ka[j] = kn[j];
  }

  // ---- deferred l reduction (m_run already group-uniform)
  #pragma unroll
  for (int nt = 0; nt < 2; ++nt) {
    l_run[nt] += __shfl_xor(l_run[nt], 16, 64);
    l_run[nt] += __shfl_xor(l_run[nt], 32, 64);
  }

  __syncthreads();   // all waves done with their P buffers before merge overlay

  // ---- in-LDS split merge (round-2 verified)
  #pragma unroll
  for (int nt = 0; nt < 2; ++nt)
    #pragma unroll
    for (int ct = 0; ct < 4; ++ct) {
      const int q = nt * 4 + ct;
      *(f32x4*)(sAB + (w << 13) + lane * 128 + ((q ^ (lane & 7)) << 4)) =
          acc[nt][ct];
    }
  if (lane < 16) {
    sM[w][0][lane] = m_run[0];
    sM[w][1][lane] = m_run[1];
    sL[w][0][lane] = l_run[0];
    sL[w][1][lane] = l_run[1];
  }
  __syncthreads();

  const float g = gamma_p[0];
  #pragma unroll
  for (int qq = 0; qq < 2; ++qq) {
    const int q = 2 * w + qq;
    const int nt = q >> 2, ct = q & 3;
    const float m0 = sM[0][nt][lr], m1 = sM[1][nt][lr];
    const float m2 = sM[2][nt][lr], m3 = sM[3][nt][lr];
    const float M = fmaxf(fmaxf(m0, m1), fmaxf(m2, m3));
    const float e0 = __expf(m0 - M), e1 = __expf(m1 - M);
    const float e2 = __expf(m2 - M), e3 = __expf(m3 - M);
    const float L = e0 * sL[0][nt][lr] + e1 * sL[1][nt][lr] +
                    e2 * sL[2][nt][lr] + e3 * sL[3][nt][lr];
    const int off = lane * 128 + ((q ^ (lane & 7)) << 4);
    const f32x4 A0 = *(const f32x4*)(sAB + off);
    const f32x4 A1 = *(const f32x4*)(sAB + 8192 + off);
    const f32x4 A2 = *(const f32x4*)(sAB + 16384 + off);
    const f32x4 A3 = *(const f32x4*)(sAB + 24576 + off);
    const float sc = g / L;
    const f32x4 o = ((A0 * e0 + A1 * e1) + (A2 * e2 + A3 * e3)) * sc;
    const int ncol = n0 + (nt << 4) + lr;
    float* dst = attn_out +
                 (((size_t)((b << 6) + (ct << 4) + (lg << 2))) << 12) + ncol;
    dst[0] = o[0];
    dst[4096] = o[1];
    dst[8192] = o[2];
    dst[12288] = o[3];
  }
}

// ---------------------------------------------------------------------------
// Kernel 3: bilinear upsample 64->128 (align_corners=True) + residual add.
// ---------------------------------------------------------------------------
__global__ __launch_bounds__(256) void upsample_residual_kernel(
    const float* __restrict__ attn_out, const float* __restrict__ x,
    float* __restrict__ out) {
  const int idx = blockIdx.x * 256 + threadIdx.x;   // 2^21 total
  const int X0 = (idx & 31) << 2;
  int rem = idx >> 5;
  const int Y = rem & 127; rem >>= 7;
  const int c = rem & 63;
  const int b = rem >> 6;

  const float sr = 63.0f / 127.0f;
  float fy = Y * sr;
  int iy = (int)fy; if (iy > 62) iy = 62;
  const float ty = fy - (float)iy;
  const float* ap = attn_out + (((size_t)(b * 64 + c)) << 12);
  const float* r0 = ap + iy * 64;
  const float* r1 = r0 + 64;

  float tmp[4];
  #pragma unroll
  for (int k = 0; k < 4; ++k) {
    const int X = X0 + k;
    float fx = X * sr;
    int ix = (int)fx; if (ix > 62) ix = 62;
    const float tx = fx - (float)ix;
    float v0 = r0[ix] + tx * (r0[ix + 1] - r0[ix]);
    float v1 = r1[ix] + tx * (r1[ix + 1] - r1[ix]);
    tmp[k] = v0 + ty * (v1 - v0);
  }
  const size_t o = (((size_t)((b * 64 + c) * 128 + Y)) << 7) + X0;
  f32x4 xv = *reinterpret_cast<const f32x4*>(x + o);
  f32x4 ov = {tmp[0] + xv[0], tmp[1] + xv[1], tmp[2] + xv[2], tmp[3] + xv[3]};
  *reinterpret_cast<f32x4*>(out + o) = ov;
}

// ---------------------------------------------------------------------------
extern "C" void kernel_launch(void* const* d_in, const int* in_sizes, int n_in,
                              void* d_out, int out_size, void* d_ws, size_t ws_size,
                              hipStream_t stream) {
  const float* x      = (const float*)d_in[0];
  const float* pool_w = (const float*)d_in[1];
  const float* pool_b = (const float*)d_in[2];
  const float* q_w    = (const float*)d_in[3];
  const float* q_b    = (const float*)d_in[4];
  const float* k_w    = (const float*)d_in[5];
  const float* k_b    = (const float*)d_in[6];
  const float* v_w    = (const float*)d_in[7];
  const float* v_b    = (const float*)d_in[8];
  const float* gamma  = (const float*)d_in[9];
  float* out = (float*)d_out;

  char* ws = (char*)d_ws;
  unsigned short* Ag   = (unsigned short*)(ws);             // 73,728 B
  unsigned short* A2g  = (unsigned short*)(ws + 81920);     // 16,384 B
  float* bias2         = (float*)(ws + 98304);              // 512 B
  unsigned short* qT   = (unsigned short*)(ws + 1048576);   // 2 MiB
  unsigned short* kT   = (unsigned short*)(ws + 3145728);   // 2 MiB
  unsigned short* vM   = (unsigned short*)(ws + 5242880);   // 4 MiB
  float* attn_out      = (float*)(ws + 9437184);            // 8 MiB

  prep_kernel<<<177, 256, 0, stream>>>(pool_w, q_w, k_w, v_w, q_b, k_b, v_b,
                                       Ag, A2g, bias2);
  convqkv_kernel<<<512, 256, 0, stream>>>(x, Ag, pool_b, A2g, bias2, qT, kT, vM);
  attn_kernel<<<1024, 256, 0, stream>>>(qT, kT, vM, gamma, attn_out);
  upsample_residual_kernel<<<8192, 256, 0, stream>>>(attn_out, x, out);
}

// Round 6
// 118.415 us; speedup vs baseline: 1.0197x; 1.0197x over previous
//
#include <hip/hip_runtime.h>

// ---------------------------------------------------------------------------
// PAM module: [prep weights] -> fused conv3x3s2+qkv (bf16 MFMA implicit GEMM)
// -> flash attention (16x16 MFMA, KV-split x4, static softmax P=2^s', LDS
// P-transpose PV) -> bilinear upsample + residual.
// Shapes: x[8][64][128][128] f32, pooled h=w=64 -> N=4096, d_qk=32, d_v=64.
// Static softmax: log2e folded into q weights; P = exp2(s') with NO max
// subtraction (valid: |s'| << 126, softmax is scale-invariant; merge = sums).
// ---------------------------------------------------------------------------

typedef __attribute__((ext_vector_type(8))) short bf16x8;   // 8 bf16 (4 VGPRs)
typedef __attribute__((ext_vector_type(4))) float f32x4;

#define DEV static __device__ __forceinline__

DEV unsigned f2bf(float f) {                  // RNE f32 -> bf16 bits
  union { float f; unsigned u; } a; a.f = f;
  return (a.u + 0x7FFFu + ((a.u >> 16) & 1u)) >> 16;
}
DEV unsigned cvtpk(float lo, float hi) {      // v_cvt_pk_bf16_f32 (RNE, 1 instr)
  unsigned r;
  asm("v_cvt_pk_bf16_f32 %0, %1, %2" : "=v"(r) : "v"(lo), "v"(hi));
  return r;
}
DEV bf16x8 mk_bf16x8(unsigned w0, unsigned w1, unsigned w2, unsigned w3) {
  union { unsigned u[4]; bf16x8 v; } x;
  x.u[0] = w0; x.u[1] = w1; x.u[2] = w2; x.u[3] = w3;
  return x.v;
}

// ---------------------------------------------------------------------------
// Kernel 0: weight prep.  Ag[oc][k=tap*64+ic] bf16 (conv A-operand, K=576);
// A2g[row][ic] bf16 (rows 0-31 q_w * log2e, 32-63 k_w, 64-127 v_w);
// bias2[128] f32 (q_b * log2e, k_b, v_b).
// ---------------------------------------------------------------------------
__global__ __launch_bounds__(256) void prep_kernel(
    const float* __restrict__ pw, const float* __restrict__ qw,
    const float* __restrict__ kw, const float* __restrict__ vw,
    const float* __restrict__ qb, const float* __restrict__ kb,
    const float* __restrict__ vb,
    unsigned short* __restrict__ Ag, unsigned short* __restrict__ A2g,
    float* __restrict__ bias2) {
  const float LOG2E = 1.4426950408889634f;
  const int i = blockIdx.x * 256 + threadIdx.x;
  if (i < 36864) {
    const int oc = i / 576, k = i - oc * 576;
    const int tap = k >> 6, ic = k & 63;
    Ag[i] = (unsigned short)f2bf(pw[(oc * 64 + ic) * 9 + tap]);
  }
  const int j = i - 36864;
  if (j >= 0 && j < 8192) {
    const int r = j >> 6, c = j & 63;
    if (r < 32)       A2g[j] = (unsigned short)f2bf(qw[r * 64 + c] * LOG2E);
    else if (r < 64)  A2g[j] = (unsigned short)f2bf(kw[(r - 32) * 64 + c]);
    else              A2g[j] = (unsigned short)f2bf(vw[(r - 64) * 64 + c]);
  }
  if (j >= 8192 && j < 8320) {
    const int r = j - 8192;
    bias2[r] = r < 32 ? qb[r] * LOG2E : (r < 64 ? kb[r - 32] : vb[r - 64]);
  }
}

// ---------------------------------------------------------------------------
// Kernel 1: fused conv3x3s2 + qkv, bf16 MFMA 16x16x32 (round-2 verified).
// ---------------------------------------------------------------------------
__global__ __launch_bounds__(256) void convqkv_kernel(
    const float* __restrict__ x, const unsigned short* __restrict__ Ag,
    const float* __restrict__ pool_b, const unsigned short* __restrict__ A2g,
    const float* __restrict__ bias2,
    unsigned short* __restrict__ qT, unsigned short* __restrict__ kT,
    unsigned short* __restrict__ vM) {
  const int b = blockIdx.x >> 6, oy = blockIdx.x & 63;
  const int t = threadIdx.x, w = t >> 6, lane = t & 63;
  const int lr = lane & 15, lg = lane >> 4;
  __shared__ unsigned short sIn[390 * 64];   // 48.75 KB, swizzled bytes
  __shared__ unsigned short sXP[64 * 64];    // 8 KB, swizzled bytes
  char* sInB = (char*)sIn;
  char* sXPB = (char*)sXP;

  bf16x8 af[18];
  {
    const unsigned short* ap = Ag + (w * 16 + lr) * 576 + (lg << 3);
    #pragma unroll
    for (int kc = 0; kc < 18; ++kc)
      af[kc] = *(const bf16x8*)(ap + kc * 32);
  }

  #pragma unroll
  for (int rr = 0; rr < 2; ++rr) {
    const int pos = t + rr * 256;
    if (pos < 390) {
      const int ky = pos / 130, xi = pos - ky * 130;
      const int iy = 2 * oy + ky - 1, ix = xi - 1;
      const bool ok = (iy >= 0) & (iy < 128) & (ix >= 0) & (ix < 128);
      const float* xs = x + ((size_t)(b * 64) * 128 + (ok ? iy : 0)) * 128 +
                        (ok ? ix : 0);
      const int sw = pos & 7;
      #pragma unroll
      for (int o = 0; o < 8; ++o) {
        float f[8];
        #pragma unroll
        for (int jj = 0; jj < 8; ++jj)
          f[jj] = ok ? xs[(size_t)(o * 8 + jj) * 16384] : 0.f;
        bf16x8 v = mk_bf16x8(cvtpk(f[0], f[1]), cvtpk(f[2], f[3]),
                             cvtpk(f[4], f[5]), cvtpk(f[6], f[7]));
        *(bf16x8*)(sInB + pos * 128 + ((o ^ sw) << 4)) = v;
      }
    }
  }
  __syncthreads();

  f32x4 acc[4];
  #pragma unroll
  for (int nt = 0; nt < 4; ++nt) acc[nt] = (f32x4){0.f, 0.f, 0.f, 0.f};
  #pragma unroll
  for (int kc = 0; kc < 18; ++kc) {
    const int tap = kc >> 1, ky = tap / 3, kx = tap - ky * 3;
    const int o = ((kc & 1) << 2) + lg;
    #pragma unroll
    for (int nt = 0; nt < 4; ++nt) {
      const int xi = 2 * (nt * 16 + lr) + kx;
      const int pos = ky * 130 + xi;
      bf16x8 bfr = *(const bf16x8*)(sInB + pos * 128 + ((o ^ (pos & 7)) << 4));
      acc[nt] = __builtin_amdgcn_mfma_f32_16x16x32_bf16(af[kc], bfr, acc[nt],
                                                        0, 0, 0);
    }
  }

  const int ocBase = w * 16 + (lg << 2);
  float pb[4];
  #pragma unroll
  for (int r = 0; r < 4; ++r) pb[r] = pool_b[ocBase + r];
  const int ocOct = ocBase >> 3;
  const int withinB = (ocBase & 7) * 2;
  #pragma unroll
  for (int nt = 0; nt < 4; ++nt) {
    const int pos = nt * 16 + lr;
    const unsigned p01 = cvtpk(acc[nt][0] + pb[0], acc[nt][1] + pb[1]);
    const unsigned p23 = cvtpk(acc[nt][2] + pb[2], acc[nt][3] + pb[3]);
    char* base = sXPB + pos * 128 + ((ocOct ^ (pos & 7)) << 4) + withinB;
    *(unsigned*)(base) = p01;
    *(unsigned*)(base + 4) = p23;
  }
  __syncthreads();

  bf16x8 a2[2][2];
  #pragma unroll
  for (int mt = 0; mt < 2; ++mt)
    #pragma unroll
    for (int kc2 = 0; kc2 < 2; ++kc2)
      a2[mt][kc2] = *(const bf16x8*)(A2g + ((2 * w + mt) * 16 + lr) * 64 +
                                     kc2 * 32 + (lg << 3));
  f32x4 acc2[2][4];
  #pragma unroll
  for (int mt = 0; mt < 2; ++mt)
    #pragma unroll
    for (int nt = 0; nt < 4; ++nt) acc2[mt][nt] = (f32x4){0.f, 0.f, 0.f, 0.f};
  #pragma unroll
  for (int kc2 = 0; kc2 < 2; ++kc2) {
    const int o2 = (kc2 << 2) + lg;
    #pragma unroll
    for (int nt = 0; nt < 4; ++nt) {
      const int pos = nt * 16 + lr;
      bf16x8 bfr = *(const bf16x8*)(sXPB + pos * 128 + ((o2 ^ (pos & 7)) << 4));
      acc2[0][nt] = __builtin_amdgcn_mfma_f32_16x16x32_bf16(a2[0][kc2], bfr,
                                                            acc2[0][nt], 0, 0, 0);
      acc2[1][nt] = __builtin_amdgcn_mfma_f32_16x16x32_bf16(a2[1][kc2], bfr,
                                                            acc2[1][nt], 0, 0, 0);
    }
  }

  const int n0g = oy << 6;
  #pragma unroll
  for (int mt = 0; mt < 2; ++mt) {
    const int rowB = (2 * w + mt) * 16 + (lg << 2);
    float b2[4];
    #pragma unroll
    for (int r = 0; r < 4; ++r) b2[r] = bias2[rowB + r];
    if (rowB < 32) {
      #pragma unroll
      for (int nt = 0; nt < 4; ++nt) {
        const int n = n0g + nt * 16 + lr;
        unsigned* dst = (unsigned*)(qT + (((size_t)(b << 12) + n) << 5) + rowB);
        dst[0] = cvtpk(acc2[mt][nt][0] + b2[0], acc2[mt][nt][1] + b2[1]);
        dst[1] = cvtpk(acc2[mt][nt][2] + b2[2], acc2[mt][nt][3] + b2[3]);
      }
    } else if (rowB < 64) {
      #pragma unroll
      for (int nt = 0; nt < 4; ++nt) {
        const int n = n0g + nt * 16 + lr;
        unsigned* dst = (unsigned*)(kT + (((size_t)(b << 12) + n) << 5) + rowB - 32);
        dst[0] = cvtpk(acc2[mt][nt][0] + b2[0], acc2[mt][nt][1] + b2[1]);
        dst[1] = cvtpk(acc2[mt][nt][2] + b2[2], acc2[mt][nt][3] + b2[3]);
      }
    } else {
      const int cv = rowB - 64;
      #pragma unroll
      for (int nt = 0; nt < 4; ++nt) {
        const int n = n0g + nt * 16 + lr;
        #pragma unroll
        for (int r = 0; r < 4; ++r)
          vM[(((size_t)(b << 6) + cv + r) << 12) + n] =
              (unsigned short)f2bf(acc2[mt][nt][r] + b2[r]);
      }
    }
  }
}

// ---------------------------------------------------------------------------
// Kernel 2: flash attention, static softmax.
// Block = (b, 32-query tile); wave w handles keys [w*1024, +1024).
// P = exp2(s') directly (no max tracking, no rescale, no cross-lane reduce in
// the loop).  P-transpose via per-wave LDS buffer, PLAIN layout (row stride
// 144 B): write banks 4lr+8j+2lg and read start-banks 4lr+16h+4lg are both
// bijective per 8-lane service group -> conflict-free (round-5's XOR broke
// this).  Split merge = plain sums.  T5 setprio around MFMA clusters.
// ---------------------------------------------------------------------------
__global__ __launch_bounds__(256) void attn_kernel(
    const unsigned short* __restrict__ qT, const unsigned short* __restrict__ kT,
    const unsigned short* __restrict__ vM, const float* __restrict__ gamma_p,
    float* __restrict__ attn_out) {
  const int t = threadIdx.x;
  const int b = blockIdx.x & 7;
  const int u = blockIdx.x >> 3;            // 0..127 query tile
  const int n0 = u << 5;
  const int w = t >> 6;                     // KV split
  const int lane = t & 63, lr = lane & 15, lg = lane >> 4;
  __shared__ float sAcc[4 * 64 * 32];       // 32 KB: Pb (loop) / merge (post)
  __shared__ float sL[4][2][16];
  char* sAB = (char*)sAcc;
  char* Pw = sAB + (w << 13);               // this wave's P buffer (4608 B used)

  const unsigned short* qp = qT + (((size_t)(b << 12) + n0 + lr) << 5) + (lg << 3);
  const bf16x8 bq0 = *(const bf16x8*)(qp);
  const bf16x8 bq1 = *(const bf16x8*)(qp + (16 << 5));

  const int kvbase = w << 10;
  const unsigned short* kbase =
      kT + (((size_t)(b << 12) + kvbase + lr) << 5) + (lg << 3);
  const unsigned short* vbase =
      vM + (((size_t)(b << 6) + lr) << 12) + kvbase + (lg << 3);

  f32x4 acc[2][4];
  #pragma unroll
  for (int i = 0; i < 2; ++i)
    #pragma unroll
    for (int j = 0; j < 4; ++j) acc[i][j] = (f32x4){0.f, 0.f, 0.f, 0.f};
  float l_run[2] = {0.f, 0.f};

  bf16x8 ka[4];
  #pragma unroll
  for (int j = 0; j < 4; ++j)
    ka[j] = *(const bf16x8*)(kbase + ((size_t)(16 * j) << 5));

  for (int km = 0; km < 1024; km += 64) {
    bf16x8 va[2][4];
    #pragma unroll
    for (int h = 0; h < 2; ++h)
      #pragma unroll
      for (int ct = 0; ct < 4; ++ct)
        va[h][ct] = *(const bf16x8*)(
            vbase + ((size_t)(ct << 4) << 12) + km + (h << 5));
    const int kmn = (km + 64) & 1023;
    bf16x8 kn[4];
    #pragma unroll
    for (int j = 0; j < 4; ++j)
      kn[j] = *(const bf16x8*)(kbase + ((size_t)(kmn + 16 * j) << 5));

    f32x4 st[2][4];
    const f32x4 z4 = {0.f, 0.f, 0.f, 0.f};
    __builtin_amdgcn_s_setprio(1);
    #pragma unroll
    for (int j = 0; j < 4; ++j) {
      st[0][j] = __builtin_amdgcn_mfma_f32_16x16x32_bf16(ka[j], bq0, z4, 0, 0, 0);
      st[1][j] = __builtin_amdgcn_mfma_f32_16x16x32_bf16(ka[j], bq1, z4, 0, 0, 0);
    }
    __builtin_amdgcn_s_setprio(0);

    // ---- static softmax numerator: P = 2^s (q pre-scaled by log2e)
    #pragma unroll
    for (int nt = 0; nt < 2; ++nt) {
      float ps0 = 0.f, ps1 = 0.f;
      #pragma unroll
      for (int j = 0; j < 4; ++j) {
        const float p0 = __builtin_amdgcn_exp2f(st[nt][j][0]);
        const float p1 = __builtin_amdgcn_exp2f(st[nt][j][1]);
        const float p2 = __builtin_amdgcn_exp2f(st[nt][j][2]);
        const float p3 = __builtin_amdgcn_exp2f(st[nt][j][3]);
        ps0 += p0 + p1;
        ps1 += p2 + p3;
        // P transpose: keys 16j+4lg..+3 at query-row nt*16+lr, slot 4j+lg
        *(uint2*)(Pw + (nt * 16 + lr) * 144 + (((j << 2) + lg) << 3)) =
            (uint2){cvtpk(p0, p1), cvtpk(p2, p3)};
      }
      l_run[nt] += ps0 + ps1;               // per-lane partial (reduced at end)
    }

    // ---- PV: B-frag = P[q=nt*16+lr][keys 32h+8lg..+7] as one b128 read
    #pragma unroll
    for (int h = 0; h < 2; ++h) {
      #pragma unroll
      for (int nt = 0; nt < 2; ++nt) {
        const bf16x8 pbf = *(const bf16x8*)(
            Pw + (nt * 16 + lr) * 144 + (((h << 3) + (lg << 1)) << 3));
        __builtin_amdgcn_s_setprio(1);
        #pragma unroll
        for (int ct = 0; ct < 4; ++ct)
          acc[nt][ct] = __builtin_amdgcn_mfma_f32_16x16x32_bf16(va[h][ct], pbf,
                                                                acc[nt][ct], 0, 0, 0);
        __builtin_amdgcn_s_setprio(0);
      }
    }
    #pragma unroll
    for (int j = 0; j < 4; ++j) ka[j] = kn[j];
  }

  // ---- deferred l reduction
  #pragma unroll
  for (int nt = 0; nt < 2; ++nt) {
    l_run[nt] += __shfl_xor(l_run[nt], 16, 64);
    l_run[nt] += __shfl_xor(l_run[nt], 32, 64);
  }

  __syncthreads();   // all waves done with their P buffers before merge overlay

  // ---- in-LDS split merge (plain sums; no max renormalization needed)
  #pragma unroll
  for (int nt = 0; nt < 2; ++nt)
    #pragma unroll
    for (int ct = 0; ct < 4; ++ct) {
      const int q = nt * 4 + ct;
      *(f32x4*)(sAB + (w << 13) + lane * 128 + ((q ^ (lane & 7)) << 4)) =
          acc[nt][ct];
    }
  if (lane < 16) {
    sL[w][0][lane] = l_run[0];
    sL[w][1][lane] = l_run[1];
  }
  __syncthreads();

  const float g = gamma_p[0];
  #pragma unroll
  for (int qq = 0; qq < 2; ++qq) {
    const int q = 2 * w + qq;
    const int nt = q >> 2, ct = q & 3;
    const float L = sL[0][nt][lr] + sL[1][nt][lr] +
                    sL[2][nt][lr] + sL[3][nt][lr];
    const int off = lane * 128 + ((q ^ (lane & 7)) << 4);
    const f32x4 A0 = *(const f32x4*)(sAB + off);
    const f32x4 A1 = *(const f32x4*)(sAB + 8192 + off);
    const f32x4 A2 = *(const f32x4*)(sAB + 16384 + off);
    const f32x4 A3 = *(const f32x4*)(sAB + 24576 + off);
    const float sc = g / L;
    const f32x4 o = ((A0 + A1) + (A2 + A3)) * sc;
    const int ncol = n0 + (nt << 4) + lr;
    float* dst = attn_out +
                 (((size_t)((b << 6) + (ct << 4) + (lg << 2))) << 12) + ncol;
    dst[0] = o[0];
    dst[4096] = o[1];
    dst[8192] = o[2];
    dst[12288] = o[3];
  }
}

// ---------------------------------------------------------------------------
// Kernel 3: bilinear upsample 64->128 (align_corners=True) + residual add.
// ---------------------------------------------------------------------------
__global__ __launch_bounds__(256) void upsample_residual_kernel(
    const float* __restrict__ attn_out, const float* __restrict__ x,
    float* __restrict__ out) {
  const int idx = blockIdx.x * 256 + threadIdx.x;   // 2^21 total
  const int X0 = (idx & 31) << 2;
  int rem = idx >> 5;
  const int Y = rem & 127; rem >>= 7;
  const int c = rem & 63;
  const int b = rem >> 6;

  const float sr = 63.0f / 127.0f;
  float fy = Y * sr;
  int iy = (int)fy; if (iy > 62) iy = 62;
  const float ty = fy - (float)iy;
  const float* ap = attn_out + (((size_t)(b * 64 + c)) << 12);
  const float* r0 = ap + iy * 64;
  const float* r1 = r0 + 64;

  float tmp[4];
  #pragma unroll
  for (int k = 0; k < 4; ++k) {
    const int X = X0 + k;
    float fx = X * sr;
    int ix = (int)fx; if (ix > 62) ix = 62;
    const float tx = fx - (float)ix;
    float v0 = r0[ix] + tx * (r0[ix + 1] - r0[ix]);
    float v1 = r1[ix] + tx * (r1[ix + 1] - r1[ix]);
    tmp[k] = v0 + ty * (v1 - v0);
  }
  const size_t o = (((size_t)((b * 64 + c) * 128 + Y)) << 7) + X0;
  f32x4 xv = *reinterpret_cast<const f32x4*>(x + o);
  f32x4 ov = {tmp[0] + xv[0], tmp[1] + xv[1], tmp[2] + xv[2], tmp[3] + xv[3]};
  *reinterpret_cast<f32x4*>(out + o) = ov;
}

// ---------------------------------------------------------------------------
extern "C" void kernel_launch(void* const* d_in, const int* in_sizes, int n_in,
                              void* d_out, int out_size, void* d_ws, size_t ws_size,
                              hipStream_t stream) {
  const float* x      = (const float*)d_in[0];
  const float* pool_w = (const float*)d_in[1];
  const float* pool_b = (const float*)d_in[2];
  const float* q_w    = (const float*)d_in[3];
  const float* q_b    = (const float*)d_in[4];
  const float* k_w    = (const float*)d_in[5];
  const float* k_b    = (const float*)d_in[6];
  const float* v_w    = (const float*)d_in[7];
  const float* v_b    = (const float*)d_in[8];
  const float* gamma  = (const float*)d_in[9];
  float* out = (float*)d_out;

  char* ws = (char*)d_ws;
  unsigned short* Ag   = (unsigned short*)(ws);             // 73,728 B
  unsigned short* A2g  = (unsigned short*)(ws + 81920);     // 16,384 B
  float* bias2         = (float*)(ws + 98304);              // 512 B
  unsigned short* qT   = (unsigned short*)(ws + 1048576);   // 2 MiB
  unsigned short* kT   = (unsigned short*)(ws + 3145728);   // 2 MiB
  unsigned short* vM   = (unsigned short*)(ws + 5242880);   // 4 MiB
  float* attn_out      = (float*)(ws + 9437184);            // 8 MiB

  prep_kernel<<<177, 256, 0, stream>>>(pool_w, q_w, k_w, v_w, q_b, k_b, v_b,
                                       Ag, A2g, bias2);
  convqkv_kernel<<<512, 256, 0, stream>>>(x, Ag, pool_b, A2g, bias2, qT, kT, vM);
  attn_kernel<<<1024, 256, 0, stream>>>(qT, kT, vM, gamma, attn_out);
  upsample_residual_kernel<<<8192, 256, 0, stream>>>(attn_out, x, out);
}

// Round 8
// 93.462 us; speedup vs baseline: 1.2920x; 1.2670x over previous
//
#include <hip/hip_runtime.h>

// ---------------------------------------------------------------------------
// PAM module: [prep weights] -> fused conv3x3s2+qkv (bf16 MFMA implicit GEMM)
// -> flash attention (query-split waves, block-shared LDS KV staging, static
// softmax P=2^s', key-split x2 over blocks w/ additive merge) -> merge ->
// bilinear upsample + residual.
// Shapes: x[8][64][128][128] f32, pooled h=w=64 -> N=4096, d_qk=32, d_v=64.
// ---------------------------------------------------------------------------

typedef __attribute__((ext_vector_type(8))) short bf16x8;   // 8 bf16 (4 VGPRs)
typedef __attribute__((ext_vector_type(4))) float f32x4;

#define DEV static __device__ __forceinline__

DEV unsigned f2bf(float f) {                  // RNE f32 -> bf16 bits
  union { float f; unsigned u; } a; a.f = f;
  return (a.u + 0x7FFFu + ((a.u >> 16) & 1u)) >> 16;
}
DEV unsigned cvtpk(float lo, float hi) {      // v_cvt_pk_bf16_f32 (RNE, 1 instr)
  unsigned r;
  asm("v_cvt_pk_bf16_f32 %0, %1, %2" : "=v"(r) : "v"(lo), "v"(hi));
  return r;
}
DEV bf16x8 mk_bf16x8(unsigned w0, unsigned w1, unsigned w2, unsigned w3) {
  union { unsigned u[4]; bf16x8 v; } x;
  x.u[0] = w0; x.u[1] = w1; x.u[2] = w2; x.u[3] = w3;
  return x.v;
}
DEV void gload_lds16(const void* g, void* l) {
  __builtin_amdgcn_global_load_lds(
      (const __attribute__((address_space(1))) void*)g,
      (__attribute__((address_space(3))) void*)l, 16, 0, 0);
}

// ---------------------------------------------------------------------------
// Kernel 0: weight prep.  Ag[oc][k=tap*64+ic] bf16 (conv A-operand, K=576);
// A2g[row][ic] bf16 (rows 0-31 q_w*log2e, 32-63 k_w, 64-127 v_w); bias2[128].
// ---------------------------------------------------------------------------
__global__ __launch_bounds__(256) void prep_kernel(
    const float* __restrict__ pw, const float* __restrict__ qw,
    const float* __restrict__ kw, const float* __restrict__ vw,
    const float* __restrict__ qb, const float* __restrict__ kb,
    const float* __restrict__ vb,
    unsigned short* __restrict__ Ag, unsigned short* __restrict__ A2g,
    float* __restrict__ bias2) {
  const float LOG2E = 1.4426950408889634f;
  const int i = blockIdx.x * 256 + threadIdx.x;
  if (i < 36864) {
    const int oc = i / 576, k = i - oc * 576;
    const int tap = k >> 6, ic = k & 63;
    Ag[i] = (unsigned short)f2bf(pw[(oc * 64 + ic) * 9 + tap]);
  }
  const int j = i - 36864;
  if (j >= 0 && j < 8192) {
    const int r = j >> 6, c = j & 63;
    if (r < 32)       A2g[j] = (unsigned short)f2bf(qw[r * 64 + c] * LOG2E);
    else if (r < 64)  A2g[j] = (unsigned short)f2bf(kw[(r - 32) * 64 + c]);
    else              A2g[j] = (unsigned short)f2bf(vw[(r - 64) * 64 + c]);
  }
  if (j >= 8192 && j < 8320) {
    const int r = j - 8192;
    bias2[r] = r < 32 ? qb[r] * LOG2E : (r < 64 ? kb[r - 32] : vb[r - 64]);
  }
}

// ---------------------------------------------------------------------------
// Kernel 1: fused conv3x3s2 + qkv, bf16 MFMA 16x16x32 (round-2 verified).
// ---------------------------------------------------------------------------
__global__ __launch_bounds__(256) void convqkv_kernel(
    const float* __restrict__ x, const unsigned short* __restrict__ Ag,
    const float* __restrict__ pool_b, const unsigned short* __restrict__ A2g,
    const float* __restrict__ bias2,
    unsigned short* __restrict__ qT, unsigned short* __restrict__ kT,
    unsigned short* __restrict__ vM) {
  const int b = blockIdx.x >> 6, oy = blockIdx.x & 63;
  const int t = threadIdx.x, w = t >> 6, lane = t & 63;
  const int lr = lane & 15, lg = lane >> 4;
  __shared__ unsigned short sIn[390 * 64];   // 48.75 KB, swizzled bytes
  __shared__ unsigned short sXP[64 * 64];    // 8 KB, swizzled bytes
  char* sInB = (char*)sIn;
  char* sXPB = (char*)sXP;

  bf16x8 af[18];
  {
    const unsigned short* ap = Ag + (w * 16 + lr) * 576 + (lg << 3);
    #pragma unroll
    for (int kc = 0; kc < 18; ++kc)
      af[kc] = *(const bf16x8*)(ap + kc * 32);
  }

  #pragma unroll
  for (int rr = 0; rr < 2; ++rr) {
    const int pos = t + rr * 256;
    if (pos < 390) {
      const int ky = pos / 130, xi = pos - ky * 130;
      const int iy = 2 * oy + ky - 1, ix = xi - 1;
      const bool ok = (iy >= 0) & (iy < 128) & (ix >= 0) & (ix < 128);
      const float* xs = x + ((size_t)(b * 64) * 128 + (ok ? iy : 0)) * 128 +
                        (ok ? ix : 0);
      const int sw = pos & 7;
      #pragma unroll
      for (int o = 0; o < 8; ++o) {
        float f[8];
        #pragma unroll
        for (int jj = 0; jj < 8; ++jj)
          f[jj] = ok ? xs[(size_t)(o * 8 + jj) * 16384] : 0.f;
        bf16x8 v = mk_bf16x8(cvtpk(f[0], f[1]), cvtpk(f[2], f[3]),
                             cvtpk(f[4], f[5]), cvtpk(f[6], f[7]));
        *(bf16x8*)(sInB + pos * 128 + ((o ^ sw) << 4)) = v;
      }
    }
  }
  __syncthreads();

  f32x4 acc[4];
  #pragma unroll
  for (int nt = 0; nt < 4; ++nt) acc[nt] = (f32x4){0.f, 0.f, 0.f, 0.f};
  #pragma unroll
  for (int kc = 0; kc < 18; ++kc) {
    const int tap = kc >> 1, ky = tap / 3, kx = tap - ky * 3;
    const int o = ((kc & 1) << 2) + lg;
    #pragma unroll
    for (int nt = 0; nt < 4; ++nt) {
      const int xi = 2 * (nt * 16 + lr) + kx;
      const int pos = ky * 130 + xi;
      bf16x8 bfr = *(const bf16x8*)(sInB + pos * 128 + ((o ^ (pos & 7)) << 4));
      acc[nt] = __builtin_amdgcn_mfma_f32_16x16x32_bf16(af[kc], bfr, acc[nt],
                                                        0, 0, 0);
    }
  }

  const int ocBase = w * 16 + (lg << 2);
  float pb[4];
  #pragma unroll
  for (int r = 0; r < 4; ++r) pb[r] = pool_b[ocBase + r];
  const int ocOct = ocBase >> 3;
  const int withinB = (ocBase & 7) * 2;
  #pragma unroll
  for (int nt = 0; nt < 4; ++nt) {
    const int pos = nt * 16 + lr;
    const unsigned p01 = cvtpk(acc[nt][0] + pb[0], acc[nt][1] + pb[1]);
    const unsigned p23 = cvtpk(acc[nt][2] + pb[2], acc[nt][3] + pb[3]);
    char* base = sXPB + pos * 128 + ((ocOct ^ (pos & 7)) << 4) + withinB;
    *(unsigned*)(base) = p01;
    *(unsigned*)(base + 4) = p23;
  }
  __syncthreads();

  bf16x8 a2[2][2];
  #pragma unroll
  for (int mt = 0; mt < 2; ++mt)
    #pragma unroll
    for (int kc2 = 0; kc2 < 2; ++kc2)
      a2[mt][kc2] = *(const bf16x8*)(A2g + ((2 * w + mt) * 16 + lr) * 64 +
                                     kc2 * 32 + (lg << 3));
  f32x4 acc2[2][4];
  #pragma unroll
  for (int mt = 0; mt < 2; ++mt)
    #pragma unroll
    for (int nt = 0; nt < 4; ++nt) acc2[mt][nt] = (f32x4){0.f, 0.f, 0.f, 0.f};
  #pragma unroll
  for (int kc2 = 0; kc2 < 2; ++kc2) {
    const int o2 = (kc2 << 2) + lg;
    #pragma unroll
    for (int nt = 0; nt < 4; ++nt) {
      const int pos = nt * 16 + lr;
      bf16x8 bfr = *(const bf16x8*)(sXPB + pos * 128 + ((o2 ^ (pos & 7)) << 4));
      acc2[0][nt] = __builtin_amdgcn_mfma_f32_16x16x32_bf16(a2[0][kc2], bfr,
                                                            acc2[0][nt], 0, 0, 0);
      acc2[1][nt] = __builtin_amdgcn_mfma_f32_16x16x32_bf16(a2[1][kc2], bfr,
                                                            acc2[1][nt], 0, 0, 0);
    }
  }

  const int n0g = oy << 6;
  #pragma unroll
  for (int mt = 0; mt < 2; ++mt) {
    const int rowB = (2 * w + mt) * 16 + (lg << 2);
    float b2[4];
    #pragma unroll
    for (int r = 0; r < 4; ++r) b2[r] = bias2[rowB + r];
    if (rowB < 32) {
      #pragma unroll
      for (int nt = 0; nt < 4; ++nt) {
        const int n = n0g + nt * 16 + lr;
        unsigned* dst = (unsigned*)(qT + (((size_t)(b << 12) + n) << 5) + rowB);
        dst[0] = cvtpk(acc2[mt][nt][0] + b2[0], acc2[mt][nt][1] + b2[1]);
        dst[1] = cvtpk(acc2[mt][nt][2] + b2[2], acc2[mt][nt][3] + b2[3]);
      }
    } else if (rowB < 64) {
      #pragma unroll
      for (int nt = 0; nt < 4; ++nt) {
        const int n = n0g + nt * 16 + lr;
        unsigned* dst = (unsigned*)(kT + (((size_t)(b << 12) + n) << 5) + rowB - 32);
        dst[0] = cvtpk(acc2[mt][nt][0] + b2[0], acc2[mt][nt][1] + b2[1]);
        dst[1] = cvtpk(acc2[mt][nt][2] + b2[2], acc2[mt][nt][3] + b2[3]);
      }
    } else {
      const int cv = rowB - 64;
      #pragma unroll
      for (int nt = 0; nt < 4; ++nt) {
        const int n = n0g + nt * 16 + lr;
        #pragma unroll
        for (int r = 0; r < 4; ++r)
          vM[(((size_t)(b << 6) + cv + r) << 12) + n] =
              (unsigned short)f2bf(acc2[mt][nt][r] + b2[r]);
      }
    }
  }
}

// ---------------------------------------------------------------------------
// Kernel 2: flash attention v7b (v7 with the bq1 row-offset fix).
// Grid 512 = (b = blk&7 [XCD pin], u = (blk>>3)&31 [128-query tile],
//             split = blk>>8 [keys split*2048..+2047]).
// Block: 4 waves, wave w owns queries u*128+w*32..+31, iterates 32 chunks of
// 64 keys shared via LDS.  Staging: global_load_lds, LINEAR plane layouts
// (no swizzle): K planes [seg 4][key 64] 16B units, V planes [seg 8][c 64].
// Reads are 2-way bank-aliased only (free).  Static softmax (P=2^s', q has
// log2e folded).  Partial numerators + L written raw; merged by merge_kernel.
// ---------------------------------------------------------------------------
__global__ __launch_bounds__(256, 2) void attn_kernel(
    const unsigned short* __restrict__ qT, const unsigned short* __restrict__ kT,
    const unsigned short* __restrict__ vM,
    float* __restrict__ attnP, float* __restrict__ Lbuf) {
  __shared__ char lds[24576];           // 2 bufs x (K 4KB | V 8KB)
  __shared__ char Plds[4][4608];        // per-wave P buffers (32 rows x 144B)
  const int t = threadIdx.x, w = t >> 6, lane = t & 63;
  const int lr = lane & 15, lg = lane >> 4;
  const int b = blockIdx.x & 7;
  const int u = (blockIdx.x >> 3) & 31;
  const int split = blockIdx.x >> 8;
  const int n0 = (u << 7) + (w << 5);   // this wave's 32 queries
  const int kb0 = split << 11;
  char* Pw = Plds[w];

  // Q B-frags: queries n0+lr (tile 0) and n0+16+lr (tile 1), all 32 channels
  const unsigned short* qp = qT + (((size_t)(b << 12) + n0 + lr) << 5) + (lg << 3);
  const bf16x8 bq0 = *(const bf16x8*)(qp);
  const bf16x8 bq1 = *(const bf16x8*)(qp + (16 << 5));   // FIX: +16 ROWS

  // staging source bases
  const unsigned short* ksrc = kT + ((size_t)(b << 12) << 5);          // [key][32]
  const unsigned short* vsrc = vM + (((size_t)(b << 6) + lane) << 12); // row=lane

  f32x4 acc[2][4];
  #pragma unroll
  for (int i = 0; i < 2; ++i)
    #pragma unroll
    for (int j = 0; j < 4; ++j) acc[i][j] = (f32x4){0.f, 0.f, 0.f, 0.f};
  float l_run[2] = {0.f, 0.f};

  // stage 64-key chunk at kb_ into buffer buf_ (each wave: 1 K + 2 V calls)
  // K plane j=w: unit = j*64+key(=lane); src = K[kb_+lane][d 8w..+7]
  // V planes k=2w,2w+1: unit = k*64+c(=lane); src = V[c=lane][kb_+8k..+7]
  #define STAGE(kb_, buf_) {                                                   \
    char* sb = lds + (buf_) * 12288;                                           \
    gload_lds16((const void*)(ksrc + (((size_t)(kb_) + lane) << 5) + (w << 3)),\
                sb + (w << 10));                                               \
    gload_lds16((const void*)(vsrc + (kb_) + (w << 4)),                        \
                sb + 4096 + (w << 11));                                        \
    gload_lds16((const void*)(vsrc + (kb_) + (w << 4) + 8),                    \
                sb + 4096 + (w << 11) + 1024);                                 \
  }

  STAGE(kb0, 0);
  __syncthreads();
  int buf = 0;

  for (int cc = 0; cc < 32; ++cc) {
    if (cc < 31) STAGE(kb0 + ((cc + 1) << 6), buf ^ 1);
    char* base = lds + buf * 12288;

    // ---- QK^T: A-frag K[key 16j+lr][d 8lg..+7] from plane lg
    f32x4 st[2][4];
    const f32x4 z4 = {0.f, 0.f, 0.f, 0.f};
    __builtin_amdgcn_s_setprio(1);
    #pragma unroll
    for (int j = 0; j < 4; ++j) {
      const bf16x8 ka =
          *(const bf16x8*)(base + (((lg << 6) + (j << 4) + lr) << 4));
      st[0][j] = __builtin_amdgcn_mfma_f32_16x16x32_bf16(ka, bq0, z4, 0, 0, 0);
      st[1][j] = __builtin_amdgcn_mfma_f32_16x16x32_bf16(ka, bq1, z4, 0, 0, 0);
    }
    __builtin_amdgcn_s_setprio(0);

    // ---- static softmax numerator: P = 2^s (q pre-scaled by log2e)
    #pragma unroll
    for (int nt = 0; nt < 2; ++nt) {
      float ps0 = 0.f, ps1 = 0.f;
      #pragma unroll
      for (int j = 0; j < 4; ++j) {
        const float p0 = __builtin_amdgcn_exp2f(st[nt][j][0]);
        const float p1 = __builtin_amdgcn_exp2f(st[nt][j][1]);
        const float p2 = __builtin_amdgcn_exp2f(st[nt][j][2]);
        const float p3 = __builtin_amdgcn_exp2f(st[nt][j][3]);
        ps0 += p0 + p1;
        ps1 += p2 + p3;
        // P transpose: keys 16j+4lg..+3 at query-row nt*16+lr, slot 4j+lg
        *(uint2*)(Pw + (nt * 16 + lr) * 144 + (((j << 2) + lg) << 3)) =
            (uint2){cvtpk(p0, p1), cvtpk(p2, p3)};
      }
      l_run[nt] += ps0 + ps1;
    }

    // ---- PV: A-frag V[c 16ct+lr][keys 32h+8lg..+7] from plane 4h+lg;
    //      B-frag P[q nt*16+lr][keys 32h+8lg..+7] from P buffer
    #pragma unroll
    for (int h = 0; h < 2; ++h) {
      #pragma unroll
      for (int nt = 0; nt < 2; ++nt) {
        const bf16x8 pbf = *(const bf16x8*)(
            Pw + (nt * 16 + lr) * 144 + (((h << 3) + (lg << 1)) << 3));
        __builtin_amdgcn_s_setprio(1);
        #pragma unroll
        for (int ct = 0; ct < 4; ++ct) {
          const bf16x8 va = *(const bf16x8*)(
              base + 4096 + (((((h << 2) + lg) << 6) + (ct << 4) + lr) << 4));
          acc[nt][ct] = __builtin_amdgcn_mfma_f32_16x16x32_bf16(va, pbf,
                                                                acc[nt][ct], 0, 0, 0);
        }
        __builtin_amdgcn_s_setprio(0);
      }
    }
    __syncthreads();   // drains vmcnt (stage of buf^1 done) + lgkm; buf reusable
    buf ^= 1;
  }

  // ---- deferred l reduction (lane's partial covers its lg's key subset)
  #pragma unroll
  for (int nt = 0; nt < 2; ++nt) {
    l_run[nt] += __shfl_xor(l_run[nt], 16, 64);
    l_run[nt] += __shfl_xor(l_run[nt], 32, 64);
  }

  // ---- write raw partial numerators + L (merged later; static softmax sums)
  float* dstP = attnP + ((size_t)split << 21);
  #pragma unroll
  for (int nt = 0; nt < 2; ++nt) {
    const int q = n0 + (nt << 4) + lr;
    #pragma unroll
    for (int ct = 0; ct < 4; ++ct)
      #pragma unroll
      for (int r = 0; r < 4; ++r) {
        const int c = (ct << 4) + (lg << 2) + r;
        dstP[((size_t)((b << 6) + c) << 12) + q] = acc[nt][ct][r];
      }
  }
  if (lane < 16) {
    Lbuf[((size_t)(split * 8 + b) << 12) + n0 + lane] = l_run[0];
    Lbuf[((size_t)(split * 8 + b) << 12) + n0 + 16 + lane] = l_run[1];
  }
}

// ---------------------------------------------------------------------------
// Kernel 2b: merge key-splits (in-place into attnP split 0):
// out = (P0 + P1) * gamma / (L0 + L1).
// ---------------------------------------------------------------------------
__global__ __launch_bounds__(256) void merge_kernel(
    float* __restrict__ attnP, const float* __restrict__ Lbuf,
    const float* __restrict__ gamma_p) {
  const int idx = blockIdx.x * 256 + threadIdx.x;   // 524288 threads x f32x4
  const size_t base4 = (size_t)idx << 2;
  const int n4 = (int)(base4 & 4095);
  const int b = (int)(base4 >> 18);                 // (base4>>12)>>6
  const f32x4 p0 = *(const f32x4*)(attnP + base4);
  const f32x4 p1 = *(const f32x4*)(attnP + (1u << 21) + base4);
  const f32x4 l0 = *(const f32x4*)(Lbuf + ((size_t)b << 12) + n4);
  const f32x4 l1 = *(const f32x4*)(Lbuf + ((size_t)(8 + b) << 12) + n4);
  const float g = gamma_p[0];
  f32x4 o;
  #pragma unroll
  for (int i = 0; i < 4; ++i) o[i] = (p0[i] + p1[i]) * g / (l0[i] + l1[i]);
  *(f32x4*)(attnP + base4) = o;
}

// ---------------------------------------------------------------------------
// Kernel 3: bilinear upsample 64->128 (align_corners=True) + residual add.
// ---------------------------------------------------------------------------
__global__ __launch_bounds__(256) void upsample_residual_kernel(
    const float* __restrict__ attn_out, const float* __restrict__ x,
    float* __restrict__ out) {
  const int idx = blockIdx.x * 256 + threadIdx.x;   // 2^21 total
  const int X0 = (idx & 31) << 2;
  int rem = idx >> 5;
  const int Y = rem & 127; rem >>= 7;
  const int c = rem & 63;
  const int b = rem >> 6;

  const float sr = 63.0f / 127.0f;
  float fy = Y * sr;
  int iy = (int)fy; if (iy > 62) iy = 62;
  const float ty = fy - (float)iy;
  const float* ap = attn_out + (((size_t)(b * 64 + c)) << 12);
  const float* r0 = ap + iy * 64;
  const float* r1 = r0 + 64;

  float tmp[4];
  #pragma unroll
  for (int k = 0; k < 4; ++k) {
    const int X = X0 + k;
    float fx = X * sr;
    int ix = (int)fx; if (ix > 62) ix = 62;
    const float tx = fx - (float)ix;
    float v0 = r0[ix] + tx * (r0[ix + 1] - r0[ix]);
    float v1 = r1[ix] + tx * (r1[ix + 1] - r1[ix]);
    tmp[k] = v0 + ty * (v1 - v0);
  }
  const size_t o = (((size_t)((b * 64 + c) * 128 + Y)) << 7) + X0;
  f32x4 xv = *reinterpret_cast<const f32x4*>(x + o);
  f32x4 ov = {tmp[0] + xv[0], tmp[1] + xv[1], tmp[2] + xv[2], tmp[3] + xv[3]};
  *reinterpret_cast<f32x4*>(out + o) = ov;
}

// ---------------------------------------------------------------------------
extern "C" void kernel_launch(void* const* d_in, const int* in_sizes, int n_in,
                              void* d_out, int out_size, void* d_ws, size_t ws_size,
                              hipStream_t stream) {
  const float* x      = (const float*)d_in[0];
  const float* pool_w = (const float*)d_in[1];
  const float* pool_b = (const float*)d_in[2];
  const float* q_w    = (const float*)d_in[3];
  const float* q_b    = (const float*)d_in[4];
  const float* k_w    = (const float*)d_in[5];
  const float* k_b    = (const float*)d_in[6];
  const float* v_w    = (const float*)d_in[7];
  const float* v_b    = (const float*)d_in[8];
  const float* gamma  = (const float*)d_in[9];
  float* out = (float*)d_out;

  char* ws = (char*)d_ws;
  unsigned short* Ag   = (unsigned short*)(ws);             // 73,728 B
  unsigned short* A2g  = (unsigned short*)(ws + 81920);     // 16,384 B
  float* bias2         = (float*)(ws + 98304);              // 512 B
  unsigned short* qT   = (unsigned short*)(ws + 1048576);   // 2 MiB
  unsigned short* kT   = (unsigned short*)(ws + 3145728);   // 2 MiB
  unsigned short* vM   = (unsigned short*)(ws + 5242880);   // 4 MiB
  float* attnP         = (float*)(ws + 9437184);            // 2 x 8 MiB splits
  float* Lbuf          = (float*)(ws + 26214400);           // 2x8x4096 f32=256KB

  prep_kernel<<<177, 256, 0, stream>>>(pool_w, q_w, k_w, v_w, q_b, k_b, v_b,
                                       Ag, A2g, bias2);
  convqkv_kernel<<<512, 256, 0, stream>>>(x, Ag, pool_b, A2g, bias2, qT, kT, vM);
  attn_kernel<<<512, 256, 0, stream>>>(qT, kT, vM, attnP, Lbuf);
  merge_kernel<<<2048, 256, 0, stream>>>(attnP, Lbuf, gamma);
  upsample_residual_kernel<<<8192, 256, 0, stream>>>(attnP, x, out);
}